// Round 7
// baseline (420.810 us; speedup 1.0000x reference)
//
#include <hip/hip_runtime.h>
#include <math.h>

#define BB 32
#define TT 8192
#define AD 128
#define NF 32
#define KW 31

// ws layout (floats):
#define WS_MT   0        // MtC2[31][128], pre-scaled by 2*log2(e)
#define WS_PQC  4096     // pqcC2[B][128], pre-scaled by 2*log2(e)
#define WS_PMAX 8192     // [B][8] chunk maxes
#define WS_PSUM 8448     // [B][8] chunk sums
#define SCRAP_A (1 << 22)   // 16 MB-offset scrap (floats)
#define SCRAP_B (2 << 22)
#define SCRAP_C (3 << 22)

typedef float f32x2 __attribute__((ext_vector_type(2)));
#define C2F 2.885390081777927f   // 2*log2(e)

// packed dual-FMA, S1 = VGPR pair, broadcast from its LO / HI 32-bit half
__device__ __forceinline__ f32x2 pk_fma_b_lo(f32x2 m, f32x2 w, f32x2 p) {
  asm("v_pk_fma_f32 %0, %1, %2, %0 op_sel_hi:[1,0,1]" : "+v"(p) : "v"(m), "v"(w));
  return p;
}
__device__ __forceinline__ f32x2 pk_fma_b_hi(f32x2 m, f32x2 w, f32x2 p) {
  asm("v_pk_fma_f32 %0, %1, %2, %0 op_sel:[0,1,0]" : "+v"(p) : "v"(m), "v"(w));
  return p;
}

// wave64 sum via DPP (VALU pipe). Valid result in lane 63.
__device__ __forceinline__ float wave_sum_dpp(float x) {
  int t;
  t = __builtin_amdgcn_update_dpp(0, __float_as_int(x), 0x111, 0xf, 0xf, true);
  x += __int_as_float(t);
  t = __builtin_amdgcn_update_dpp(0, __float_as_int(x), 0x112, 0xf, 0xf, true);
  x += __int_as_float(t);
  t = __builtin_amdgcn_update_dpp(0, __float_as_int(x), 0x114, 0xf, 0xf, true);
  x += __int_as_float(t);
  t = __builtin_amdgcn_update_dpp(0, __float_as_int(x), 0x118, 0xf, 0xf, true);
  x += __int_as_float(t);
  t = __builtin_amdgcn_update_dpp(0, __float_as_int(x), 0x142, 0xa, 0xf, true);
  x += __int_as_float(t);
  t = __builtin_amdgcn_update_dpp(0, __float_as_int(x), 0x143, 0xc, 0xf, true);
  x += __int_as_float(t);
  return x;
}

// ---------------- kernel 0: tiny precompute ----------------
__global__ void __launch_bounds__(128) precompute_kernel(
    const float* __restrict__ query, const float* __restrict__ conv_w,
    const float* __restrict__ conv_b, const float* __restrict__ L_w,
    const float* __restrict__ W_w, const float* __restrict__ W_b,
    float* __restrict__ ws) {
  const int a = threadIdx.x;
  const int blk = blockIdx.x;
  if (blk < BB) {
    float acc = W_b[a];
    const float* q = query + blk * AD;
    const float* w = W_w + a * AD;
#pragma unroll 8
    for (int d = 0; d < AD; ++d) acc = fmaf(q[d], w[d], acc);
    float c0 = 0.f;
#pragma unroll
    for (int f = 0; f < NF; ++f) c0 = fmaf(L_w[a * NF + f], conv_b[f], c0);
    ws[WS_PQC + blk * AD + a] = (acc + c0) * C2F;
  } else {
#pragma unroll 1
    for (int k = 0; k < KW; ++k) {
      float m = 0.f;
#pragma unroll
      for (int f = 0; f < NF; ++f) m = fmaf(L_w[a * NF + f], conv_w[f * KW + k], m);
      ws[WS_MT + k * AD + a] = m * C2F;
    }
  }
}

// ---------------- kernel 1: R6 structure, rep x2 (rep0 -> out, rep1 -> scrap) ----------------
__global__ void __launch_bounds__(256, 3) lsa_u_kernel(
    const float* __restrict__ enc, const float* __restrict__ cum,
    const int* __restrict__ chars, const float* __restrict__ v_w,
    const float* __restrict__ ws, float* __restrict__ out, float* __restrict__ scrap) {
  __shared__ __attribute__((aligned(16))) float lcum[160];
  const int b = blockIdx.y;
  const int t0 = blockIdx.x * 128;

  for (int i = threadIdx.x; i < 160; i += 256) {
    int g = t0 - 16 + i;
    lcum[i] = (g >= 0 && g < TT) ? cum[b * TT + g] : 0.f;
  }
  __syncthreads();

  const int lane = threadIdx.x & 63;
  const int wv = threadIdx.x >> 6;
  const int a0 = lane * 2;

  f32x2 Mv[KW];
  {
    const float* mtbase = ws + WS_MT + a0;
#pragma unroll
    for (int k = 0; k < KW; ++k) {
      const float* addr = mtbase + k * AD;
      asm volatile("global_load_dwordx2 %0, %1, off" : "=v"(Mv[k]) : "v"(addr));
    }
    asm volatile("s_waitcnt vmcnt(0)" ::: "memory");
  }

  const f32x2 pqC = *(const f32x2*)&ws[WS_PQC + b * AD + a0];
  const float2 vvw = *(const float2*)&v_w[a0];
  const float w0n = -2.f * vvw.x, w1n = -2.f * vvw.y, vsum = vvw.x + vvw.y;
  const f32x2 c2v = {C2F, C2F};

  const int ts_w = t0 + wv * 32;
  const float* encb = enc + ((size_t)b * TT + ts_w) * AD + a0;
  const int* chb = chars + b * TT + ts_w;

#pragma unroll 1
  for (int rep = 0; rep < 2; ++rep) {
    float* uout = (rep ? scrap : out) + (size_t)b * TT + ts_w;
    f32x2 ecur[8];
#pragma unroll
    for (int j = 0; j < 8; ++j) ecur[j] = *(const f32x2*)(encb + (size_t)j * AD);

#pragma unroll 1
    for (int g = 0; g < 4; ++g) {
      const int tloc = g * 8;
      f32x2 enx[8];
      if (g < 3) {
#pragma unroll
        for (int j = 0; j < 8; ++j)
          enx[j] = *(const f32x2*)(encb + (size_t)(tloc + 8 + j) * AD);
      }
      float fw[40];
      const float4* w4 = (const float4*)&lcum[wv * 32 + tloc];
#pragma unroll
      for (int m = 0; m < 10; ++m) {
        float4 f = w4[m];
        fw[4 * m] = f.x; fw[4 * m + 1] = f.y; fw[4 * m + 2] = f.z; fw[4 * m + 3] = f.w;
      }
      f32x2 sw[20];
#pragma unroll
      for (int m = 0; m < 20; ++m) { sw[m].x = fw[2 * m]; sw[m].y = fw[2 * m + 1]; }

      float r[8];
#pragma unroll
      for (int j = 0; j < 8; ++j) {
        f32x2 p = pqC;
#pragma unroll
        for (int k = 0; k < KW; ++k) {
          const int i = j + k + 1;
          if ((i & 1) == 0) p = pk_fma_b_lo(Mv[k], sw[i >> 1], p);
          else              p = pk_fma_b_hi(Mv[k], sw[i >> 1], p);
        }
        const f32x2 xin = ecur[j] * c2v + p;
        const float z0 = __builtin_amdgcn_exp2f(xin.x);
        const float z1 = __builtin_amdgcn_exp2f(xin.y);
        const float r0 = __builtin_amdgcn_rcpf(z0 + 1.f);
        const float r1 = __builtin_amdgcn_rcpf(z1 + 1.f);
        const float s = fmaf(w0n, r0, fmaf(w1n, r1, vsum));
        r[j] = wave_sum_dpp(s);
      }
      if (lane == 63) {
        const int4 c0 = *(const int4*)(chb + tloc);
        const int4 c1 = *(const int4*)(chb + tloc + 4);
        float4 o0, o1;
        o0.x = c0.x ? r[0] : 0.f; o0.y = c0.y ? r[1] : 0.f;
        o0.z = c0.z ? r[2] : 0.f; o0.w = c0.w ? r[3] : 0.f;
        o1.x = c1.x ? r[4] : 0.f; o1.y = c1.y ? r[5] : 0.f;
        o1.z = c1.z ? r[6] : 0.f; o1.w = c1.w ? r[7] : 0.f;
        *(float4*)(uout + tloc) = o0;
        *(float4*)(uout + tloc + 4) = o1;
      }
      if (g < 3) {
#pragma unroll
        for (int j = 0; j < 8; ++j) ecur[j] = enx[j];
      }
    }
  }
}

// ---------------- diagnostic: full2 minus reduce/store (running accumulator) ----------------
__global__ void __launch_bounds__(256, 3) lsa_u_nored(
    const float* __restrict__ enc, const float* __restrict__ cum,
    const float* __restrict__ v_w, const float* __restrict__ ws,
    float* __restrict__ scrap) {
  __shared__ __attribute__((aligned(16))) float lcum[160];
  const int b = blockIdx.y;
  const int t0 = blockIdx.x * 128;
  for (int i = threadIdx.x; i < 160; i += 256) {
    int g = t0 - 16 + i;
    lcum[i] = (g >= 0 && g < TT) ? cum[b * TT + g] : 0.f;
  }
  __syncthreads();
  const int lane = threadIdx.x & 63;
  const int wv = threadIdx.x >> 6;
  const int a0 = lane * 2;
  f32x2 Mv[KW];
  {
    const float* mtbase = ws + WS_MT + a0;
#pragma unroll
    for (int k = 0; k < KW; ++k) {
      const float* addr = mtbase + k * AD;
      asm volatile("global_load_dwordx2 %0, %1, off" : "=v"(Mv[k]) : "v"(addr));
    }
    asm volatile("s_waitcnt vmcnt(0)" ::: "memory");
  }
  const f32x2 pqC = *(const f32x2*)&ws[WS_PQC + b * AD + a0];
  const float2 vvw = *(const float2*)&v_w[a0];
  const float w0n = -2.f * vvw.x, w1n = -2.f * vvw.y, vsum = vvw.x + vvw.y;
  const f32x2 c2v = {C2F, C2F};
  const int ts_w = t0 + wv * 32;
  const float* encb = enc + ((size_t)b * TT + ts_w) * AD + a0;

#pragma unroll 1
  for (int rep = 0; rep < 2; ++rep) {
    float racc = 0.f;
    f32x2 ecur[8];
#pragma unroll
    for (int j = 0; j < 8; ++j) ecur[j] = *(const f32x2*)(encb + (size_t)j * AD);
#pragma unroll 1
    for (int g = 0; g < 4; ++g) {
      const int tloc = g * 8;
      f32x2 enx[8];
      if (g < 3) {
#pragma unroll
        for (int j = 0; j < 8; ++j)
          enx[j] = *(const f32x2*)(encb + (size_t)(tloc + 8 + j) * AD);
      }
      float fw[40];
      const float4* w4 = (const float4*)&lcum[wv * 32 + tloc];
#pragma unroll
      for (int m = 0; m < 10; ++m) {
        float4 f = w4[m];
        fw[4 * m] = f.x; fw[4 * m + 1] = f.y; fw[4 * m + 2] = f.z; fw[4 * m + 3] = f.w;
      }
      f32x2 sw[20];
#pragma unroll
      for (int m = 0; m < 20; ++m) { sw[m].x = fw[2 * m]; sw[m].y = fw[2 * m + 1]; }
#pragma unroll
      for (int j = 0; j < 8; ++j) {
        f32x2 p = pqC;
#pragma unroll
        for (int k = 0; k < KW; ++k) {
          const int i = j + k + 1;
          if ((i & 1) == 0) p = pk_fma_b_lo(Mv[k], sw[i >> 1], p);
          else              p = pk_fma_b_hi(Mv[k], sw[i >> 1], p);
        }
        const f32x2 xin = ecur[j] * c2v + p;
        const float z0 = __builtin_amdgcn_exp2f(xin.x);
        const float z1 = __builtin_amdgcn_exp2f(xin.y);
        const float r0 = __builtin_amdgcn_rcpf(z0 + 1.f);
        const float r1 = __builtin_amdgcn_rcpf(z1 + 1.f);
        racc += fmaf(w0n, r0, fmaf(w1n, r1, vsum));   // no reduce, no store
      }
      if (g < 3) {
#pragma unroll
        for (int j = 0; j < 8; ++j) ecur[j] = enx[j];
      }
    }
    scrap[(size_t)rep * (BB * 2048 * 8) +
          ((size_t)b * 64 + blockIdx.x) * 256 + threadIdx.x] = racc;
  }
}

// ---------------- candidate: t-per-lane, in-lane dot, LDS-broadcast M ----------------
__global__ void __launch_bounds__(256, 4) lsa_u_tpl(
    const float* __restrict__ enc, const float* __restrict__ cum,
    const int* __restrict__ chars, const float* __restrict__ v_w,
    const float* __restrict__ ws, float* __restrict__ scrap) {
  __shared__ float lM[KW * AD];   // Mt[k][a] * C2F — uniform broadcast reads
  __shared__ float lpq[AD];
  __shared__ float lv[AD];
  __shared__ float lw[288];       // cum[t0-16 .. t0+271]
  const int b = blockIdx.y;
  const int t0 = blockIdx.x * 256;
  const int tid = threadIdx.x;

  for (int i = tid; i < (KW * AD) / 4; i += 256)
    ((float4*)lM)[i] = ((const float4*)(ws + WS_MT))[i];
  if (tid < AD) {
    lpq[tid] = ws[WS_PQC + b * AD + tid];
    lv[tid] = v_w[tid];
  }
  for (int i = tid; i < 288; i += 256) {
    int g = t0 - 16 + i;
    lw[i] = (g >= 0 && g < TT) ? cum[b * TT + g] : 0.f;
  }
  __syncthreads();

  const int t = t0 + tid;               // lane owns one t
  const int dt = tid;
  // per-lane conv window, packed into 16 f32x2 for the op_sel pk_fma
  f32x2 wreg[16];
#pragma unroll
  for (int m = 0; m < 16; ++m) { wreg[m].x = lw[dt + 1 + 2 * m]; wreg[m].y = lw[dt + 2 + 2 * m]; }

  const float* er = enc + ((size_t)b * TT + t) * AD;
  const int ch = chars[b * TT + t];

#pragma unroll 1
  for (int rep = 0; rep < 2; ++rep) {
    float uacc = 0.f;
    f32x2 ecur[4];
#pragma unroll
    for (int i = 0; i < 4; ++i) ecur[i] = *(const f32x2*)(er + 2 * i);
#pragma unroll 1
    for (int o = 0; o < 16; ++o) {
      const int a0 = o * 8;
      f32x2 enx[4];
      if (o < 15) {
#pragma unroll
        for (int i = 0; i < 4; ++i) enx[i] = *(const f32x2*)(er + a0 + 8 + 2 * i);
      }
      f32x2 p0 = {0.f, 0.f}, p1 = {0.f, 0.f}, p2 = {0.f, 0.f}, p3 = {0.f, 0.f};
#pragma unroll
      for (int k = 0; k < KW; ++k) {
        const float4 mA = *(const float4*)&lM[k * AD + a0];       // uniform broadcast
        const float4 mB = *(const float4*)&lM[k * AD + a0 + 4];
        f32x2 m0; m0.x = mA.x; m0.y = mA.y;
        f32x2 m1; m1.x = mA.z; m1.y = mA.w;
        f32x2 m2; m2.x = mB.x; m2.y = mB.y;
        f32x2 m3; m3.x = mB.z; m3.y = mB.w;
        const f32x2 wr = wreg[k >> 1];
        if ((k & 1) == 0) {
          p0 = pk_fma_b_lo(m0, wr, p0); p1 = pk_fma_b_lo(m1, wr, p1);
          p2 = pk_fma_b_lo(m2, wr, p2); p3 = pk_fma_b_lo(m3, wr, p3);
        } else {
          p0 = pk_fma_b_hi(m0, wr, p0); p1 = pk_fma_b_hi(m1, wr, p1);
          p2 = pk_fma_b_hi(m2, wr, p2); p3 = pk_fma_b_hi(m3, wr, p3);
        }
      }
      const float4 pqA = *(const float4*)&lpq[a0];
      const float4 pqB = *(const float4*)&lpq[a0 + 4];
      const float4 vA = *(const float4*)&lv[a0];
      const float4 vB = *(const float4*)&lv[a0 + 4];
      f32x2 x0 = {pqA.x, pqA.y}, x1 = {pqA.z, pqA.w};
      f32x2 x2 = {pqB.x, pqB.y}, x3 = {pqB.z, pqB.w};
      x0 += p0 + ecur[0] * C2F; x1 += p1 + ecur[1] * C2F;
      x2 += p2 + ecur[2] * C2F; x3 += p3 + ecur[3] * C2F;
      const float z[8] = {x0.x, x0.y, x1.x, x1.y, x2.x, x2.y, x3.x, x3.y};
      const float vv[8] = {vA.x, vA.y, vA.z, vA.w, vB.x, vB.y, vB.z, vB.w};
#pragma unroll
      for (int i = 0; i < 8; ++i) {
        const float e2 = __builtin_amdgcn_exp2f(z[i]);
        const float rc = __builtin_amdgcn_rcpf(e2 + 1.f);
        uacc = fmaf(vv[i], fmaf(-2.f, rc, 1.f), uacc);   // v*tanh
      }
      if (o < 15) {
#pragma unroll
        for (int i = 0; i < 4; ++i) ecur[i] = enx[i];
      }
    }
    scrap[(size_t)rep * (BB * TT) + (size_t)b * TT + t] = ch ? uacc : 0.f;
  }
}

// ---------------- softmax ----------------
__global__ void __launch_bounds__(256) smax_partial(
    const float* __restrict__ u, float* __restrict__ ws) {
  __shared__ float rm[4], rs[4];
  const int c = blockIdx.x, b = blockIdx.y;
  const float* ub = u + (size_t)b * TT + c * 1024;
  const int tid = threadIdx.x;
  const int lane = tid & 63, wv = tid >> 6;
  const float v0 = ub[tid], v1 = ub[tid + 256], v2 = ub[tid + 512], v3 = ub[tid + 768];
  float mx = fmaxf(fmaxf(v0, v1), fmaxf(v2, v3));
#pragma unroll
  for (int off = 32; off >= 1; off >>= 1) mx = fmaxf(mx, __shfl_xor(mx, off));
  if (lane == 0) rm[wv] = mx;
  __syncthreads();
  mx = fmaxf(fmaxf(rm[0], rm[1]), fmaxf(rm[2], rm[3]));
  float sum = __expf(v0 - mx) + __expf(v1 - mx) + __expf(v2 - mx) + __expf(v3 - mx);
#pragma unroll
  for (int off = 32; off >= 1; off >>= 1) sum += __shfl_xor(sum, off);
  if (lane == 0) rs[wv] = sum;
  __syncthreads();
  if (tid == 0) {
    ws[WS_PMAX + b * 8 + c] = mx;
    ws[WS_PSUM + b * 8 + c] = rs[0] + rs[1] + rs[2] + rs[3];
  }
}

__global__ void __launch_bounds__(256) smax_norm(
    float* __restrict__ uio, const float* __restrict__ ws) {
  const int c = blockIdx.x, b = blockIdx.y;
  float gm = -1e30f;
#pragma unroll
  for (int i = 0; i < 8; ++i) gm = fmaxf(gm, ws[WS_PMAX + b * 8 + i]);
  float gs = 0.f;
#pragma unroll
  for (int i = 0; i < 8; ++i)
    gs += ws[WS_PSUM + b * 8 + i] * __expf(ws[WS_PMAX + b * 8 + i] - gm);
  const float inv = 1.f / gs;
  float* ub = uio + (size_t)b * TT + c * 1024;
  const int tid = threadIdx.x;
#pragma unroll
  for (int i = 0; i < 4; ++i) {
    const int idx = tid + i * 256;
    ub[idx] = __expf(ub[idx] - gm) * inv;
  }
}

extern "C" void kernel_launch(void* const* d_in, const int* in_sizes, int n_in,
                              void* d_out, int out_size, void* d_ws, size_t ws_size,
                              hipStream_t stream) {
  const float* enc    = (const float*)d_in[0];
  const float* query  = (const float*)d_in[1];
  const float* cum    = (const float*)d_in[2];
  const int*   chars  = (const int*)d_in[3];
  const float* conv_w = (const float*)d_in[5];
  const float* conv_b = (const float*)d_in[6];
  const float* L_w    = (const float*)d_in[7];
  const float* W_w    = (const float*)d_in[8];
  const float* W_b    = (const float*)d_in[9];
  const float* v_w    = (const float*)d_in[10];
  float* ws  = (float*)d_ws;
  float* out = (float*)d_out;

  hipLaunchKernelGGL(precompute_kernel, dim3(BB + 1), dim3(AD), 0, stream,
                     query, conv_w, conv_b, L_w, W_w, W_b, ws);
  hipLaunchKernelGGL(lsa_u_kernel, dim3(TT / 128, BB), dim3(256), 0, stream,
                     enc, cum, chars, v_w, ws, out, ws + SCRAP_A);
  hipLaunchKernelGGL(smax_partial, dim3(8, BB), dim3(256), 0, stream, out, ws);
  hipLaunchKernelGGL(smax_norm, dim3(8, BB), dim3(256), 0, stream, out, ws);
  hipLaunchKernelGGL(lsa_u_nored, dim3(TT / 128, BB), dim3(256), 0, stream,
                     enc, cum, v_w, ws, ws + SCRAP_B);
  hipLaunchKernelGGL(lsa_u_tpl, dim3(TT / 256, BB), dim3(256), 0, stream,
                     enc, cum, chars, v_w, ws, ws + SCRAP_C);
}

// Round 10
// 347.014 us; speedup vs baseline: 1.2127x; 1.2127x over previous
//
#include <hip/hip_runtime.h>
#include <math.h>

#define BB 32
#define TT 8192
#define AD 128
#define NF 32
#define KW 31

// ws layout (floats):
#define WS_MT   0        // MtC2[31][128], pre-scaled by 2*log2(e)
#define WS_PQC  4096     // pqcC2[B][128], pre-scaled by 2*log2(e)
#define WS_PMAX 8192     // [B][8] chunk maxes
#define WS_PSUM 8448     // [B][8] chunk sums
#define SCRAP_A (1 << 22)   // 16 MB-offset scrap (floats)

typedef float f32x2 __attribute__((ext_vector_type(2)));
typedef float f32x4 __attribute__((ext_vector_type(4)));
#define C2F 2.885390081777927f   // 2*log2(e)

// packed dual-FMA: m from SGPR pair (wave-uniform M), w = per-lane window pair,
// broadcast from its LO / HI 32-bit half via op_sel. p += m * broadcast(w).
__device__ __forceinline__ f32x2 pk_fma_sm_lo(f32x2 m, f32x2 w, f32x2 p) {
  asm("v_pk_fma_f32 %0, %1, %2, %0 op_sel_hi:[1,0,1]" : "+v"(p) : "s"(m), "v"(w));
  return p;
}
__device__ __forceinline__ f32x2 pk_fma_sm_hi(f32x2 m, f32x2 w, f32x2 p) {
  asm("v_pk_fma_f32 %0, %1, %2, %0 op_sel:[0,1,0]" : "+v"(p) : "s"(m), "v"(w));
  return p;
}

// ---------------- kernel 0: tiny precompute ----------------
__global__ void __launch_bounds__(128) precompute_kernel(
    const float* __restrict__ query, const float* __restrict__ conv_w,
    const float* __restrict__ conv_b, const float* __restrict__ L_w,
    const float* __restrict__ W_w, const float* __restrict__ W_b,
    float* __restrict__ ws) {
  const int a = threadIdx.x;
  const int blk = blockIdx.x;
  if (blk < BB) {
    float acc = W_b[a];
    const float* q = query + blk * AD;
    const float* w = W_w + a * AD;
#pragma unroll 8
    for (int d = 0; d < AD; ++d) acc = fmaf(q[d], w[d], acc);
    float c0 = 0.f;
#pragma unroll
    for (int f = 0; f < NF; ++f) c0 = fmaf(L_w[a * NF + f], conv_b[f], c0);
    ws[WS_PQC + blk * AD + a] = (acc + c0) * C2F;
  } else {
#pragma unroll 1
    for (int k = 0; k < KW; ++k) {
      float m = 0.f;
#pragma unroll
      for (int f = 0; f < NF; ++f) m = fmaf(L_w[a * NF + f], conv_w[f * KW + k], m);
      ws[WS_MT + k * AD + a] = m * C2F;
    }
  }
}

// ---------------- kernel 1: t-per-lane, M via scalar pipe ----------------
// grid (T/256, B), block 256. Lane owns one t; all 128 channels in-lane.
// M read as wave-uniform scalar loads feeding pk_fma's SGPR operand.
// rep x3: rep0 -> d_out (correctness), reps 1-2 -> scrap (visibility).
__global__ void __launch_bounds__(256, 4) lsa_u_tps(
    const float* __restrict__ enc, const float* __restrict__ cum,
    const int* __restrict__ chars, const float* __restrict__ v_w,
    const float* __restrict__ ws, float* __restrict__ out, float* __restrict__ scrap) {
  __shared__ float lw[288];
  const int b = blockIdx.y;
  const int t0 = blockIdx.x * 256;
  const int tid = threadIdx.x;
  for (int i = tid; i < 288; i += 256) {
    int g = t0 - 16 + i;
    lw[i] = (g >= 0 && g < TT) ? cum[b * TT + g] : 0.f;
  }
  __syncthreads();

  // per-lane conv window in regs: wreg[m] = (cum[t-15+2m], cum[t-14+2m])
  f32x2 wreg[16];
#pragma unroll
  for (int m = 0; m < 16; ++m) {
    wreg[m].x = lw[tid + 1 + 2 * m];
    wreg[m].y = lw[tid + 2 + 2 * m];
  }

  const int t = t0 + tid;
  const float* er = enc + ((size_t)b * TT + t) * AD;
  const float* Mt = ws + WS_MT;            // wave-uniform
  const float* pqb = ws + WS_PQC + b * AD; // wave-uniform
  const int ch = chars[b * TT + t];
  const f32x2 c2v = {C2F, C2F};

#pragma unroll 1
  for (int rep = 0; rep < 3; ++rep) {
    float uacc = 0.f;
    // enc prefetch pipeline: current (eA), next (eB), loading (eC)
    f32x4 eA0 = *(const f32x4*)(er + 0), eA1 = *(const f32x4*)(er + 4);
    f32x4 eB0 = *(const f32x4*)(er + 8), eB1 = *(const f32x4*)(er + 12);
#pragma unroll 1
    for (int o = 0; o < 16; ++o) {
      const int a0 = o * 8;
      f32x4 eC0, eC1;
      if (o < 14) {
        eC0 = *(const f32x4*)(er + a0 + 16);
        eC1 = *(const f32x4*)(er + a0 + 20);
      }
      f32x2 p0 = {0.f, 0.f}, p1 = {0.f, 0.f}, p2 = {0.f, 0.f}, p3 = {0.f, 0.f};
#pragma unroll
      for (int k = 0; k < KW; ++k) {
        // wave-uniform M pairs -> scalar loads -> SGPR operand of pk_fma
        const f32x2 m0 = *(const f32x2*)&Mt[k * AD + a0];
        const f32x2 m1 = *(const f32x2*)&Mt[k * AD + a0 + 2];
        const f32x2 m2 = *(const f32x2*)&Mt[k * AD + a0 + 4];
        const f32x2 m3 = *(const f32x2*)&Mt[k * AD + a0 + 6];
        const f32x2 wr = wreg[k >> 1];   // k even: LO half, k odd: HI half
        if ((k & 1) == 0) {
          p0 = pk_fma_sm_lo(m0, wr, p0); p1 = pk_fma_sm_lo(m1, wr, p1);
          p2 = pk_fma_sm_lo(m2, wr, p2); p3 = pk_fma_sm_lo(m3, wr, p3);
        } else {
          p0 = pk_fma_sm_hi(m0, wr, p0); p1 = pk_fma_sm_hi(m1, wr, p1);
          p2 = pk_fma_sm_hi(m2, wr, p2); p3 = pk_fma_sm_hi(m3, wr, p3);
        }
      }
      // epilogue: x = conv + pq + enc*C2F  (all pre-scaled by 2*log2e)
      const f32x2 pq0 = *(const f32x2*)&pqb[a0];
      const f32x2 pq1 = *(const f32x2*)&pqb[a0 + 2];
      const f32x2 pq2 = *(const f32x2*)&pqb[a0 + 4];
      const f32x2 pq3 = *(const f32x2*)&pqb[a0 + 6];
      f32x2 ex0; ex0.x = eA0.x; ex0.y = eA0.y;
      f32x2 ex1; ex1.x = eA0.z; ex1.y = eA0.w;
      f32x2 ex2; ex2.x = eA1.x; ex2.y = eA1.y;
      f32x2 ex3; ex3.x = eA1.z; ex3.y = eA1.w;
      const f32x2 x0 = ex0 * c2v + (p0 + pq0);
      const f32x2 x1 = ex1 * c2v + (p1 + pq1);
      const f32x2 x2 = ex2 * c2v + (p2 + pq2);
      const f32x2 x3 = ex3 * c2v + (p3 + pq3);
      const float z[8] = {x0.x, x0.y, x1.x, x1.y, x2.x, x2.y, x3.x, x3.y};
#pragma unroll
      for (int i = 0; i < 8; ++i) {
        const float e2 = __builtin_amdgcn_exp2f(z[i]);
        const float rc = __builtin_amdgcn_rcpf(e2 + 1.f);
        const float h = fmaf(-2.f, rc, 1.f);          // tanh
        uacc = fmaf(v_w[a0 + i], h, uacc);            // v uniform -> SGPR
      }
      if (o < 15) {
        eA0 = eB0; eA1 = eB1;
        if (o < 14) { eB0 = eC0; eB1 = eC1; }
      }
    }
    const float uo = ch ? uacc : 0.f;
    if (rep == 0) out[(size_t)b * TT + t] = uo;
    else scrap[(size_t)(rep - 1) * (BB * TT) + (size_t)b * TT + t] = uo;
  }
}

// ---------------- kernel 2a: per-chunk max & sumexp ----------------
__global__ void __launch_bounds__(256) smax_partial(
    const float* __restrict__ u, float* __restrict__ ws) {
  __shared__ float rm[4], rs[4];
  const int c = blockIdx.x, b = blockIdx.y;
  const float* ub = u + (size_t)b * TT + c * 1024;
  const int tid = threadIdx.x;
  const int lane = tid & 63, wv = tid >> 6;
  const float v0 = ub[tid], v1 = ub[tid + 256], v2 = ub[tid + 512], v3 = ub[tid + 768];
  float mx = fmaxf(fmaxf(v0, v1), fmaxf(v2, v3));
#pragma unroll
  for (int off = 32; off >= 1; off >>= 1) mx = fmaxf(mx, __shfl_xor(mx, off));
  if (lane == 0) rm[wv] = mx;
  __syncthreads();
  mx = fmaxf(fmaxf(rm[0], rm[1]), fmaxf(rm[2], rm[3]));
  float sum = __expf(v0 - mx) + __expf(v1 - mx) + __expf(v2 - mx) + __expf(v3 - mx);
#pragma unroll
  for (int off = 32; off >= 1; off >>= 1) sum += __shfl_xor(sum, off);
  if (lane == 0) rs[wv] = sum;
  __syncthreads();
  if (tid == 0) {
    ws[WS_PMAX + b * 8 + c] = mx;
    ws[WS_PSUM + b * 8 + c] = rs[0] + rs[1] + rs[2] + rs[3];
  }
}

// ---------------- kernel 2b: normalize (in-place on d_out) ----------------
__global__ void __launch_bounds__(256) smax_norm(
    float* __restrict__ uio, const float* __restrict__ ws) {
  const int c = blockIdx.x, b = blockIdx.y;
  float gm = -1e30f;
#pragma unroll
  for (int i = 0; i < 8; ++i) gm = fmaxf(gm, ws[WS_PMAX + b * 8 + i]);
  float gs = 0.f;
#pragma unroll
  for (int i = 0; i < 8; ++i)
    gs += ws[WS_PSUM + b * 8 + i] * __expf(ws[WS_PMAX + b * 8 + i] - gm);
  const float inv = 1.f / gs;
  float* ub = uio + (size_t)b * TT + c * 1024;
  const int tid = threadIdx.x;
#pragma unroll
  for (int i = 0; i < 4; ++i) {
    const int idx = tid + i * 256;
    ub[idx] = __expf(ub[idx] - gm) * inv;
  }
}

extern "C" void kernel_launch(void* const* d_in, const int* in_sizes, int n_in,
                              void* d_out, int out_size, void* d_ws, size_t ws_size,
                              hipStream_t stream) {
  const float* enc    = (const float*)d_in[0];
  const float* query  = (const float*)d_in[1];
  const float* cum    = (const float*)d_in[2];
  const int*   chars  = (const int*)d_in[3];
  // d_in[4] = t (unused)
  const float* conv_w = (const float*)d_in[5];
  const float* conv_b = (const float*)d_in[6];
  const float* L_w    = (const float*)d_in[7];
  const float* W_w    = (const float*)d_in[8];
  const float* W_b    = (const float*)d_in[9];
  const float* v_w    = (const float*)d_in[10];
  float* ws  = (float*)d_ws;
  float* out = (float*)d_out;

  hipLaunchKernelGGL(precompute_kernel, dim3(BB + 1), dim3(AD), 0, stream,
                     query, conv_w, conv_b, L_w, W_w, W_b, ws);
  hipLaunchKernelGGL(lsa_u_tps, dim3(TT / 256, BB), dim3(256), 0, stream,
                     enc, cum, chars, v_w, ws, out, ws + SCRAP_A);
  hipLaunchKernelGGL(smax_partial, dim3(8, BB), dim3(256), 0, stream, out, ws);
  hipLaunchKernelGGL(smax_norm, dim3(8, BB), dim3(256), 0, stream, out, ws);
}